// Round 2
// baseline (244.114 us; speedup 1.0000x reference)
//
#include <hip/hip_runtime.h>

#define B_ 8
#define N_ 2048
#define D_ 1024

using u16 = unsigned short;
typedef __attribute__((ext_vector_type(8))) short short8;
typedef __attribute__((ext_vector_type(4))) float f32x4;
typedef __attribute__((ext_vector_type(4))) float float4v;
typedef __attribute__((ext_vector_type(4))) int int4v;

static __device__ __forceinline__ float bf2f(u16 h) {
  return __uint_as_float(((unsigned)h) << 16);
}
static __device__ __forceinline__ u16 f2bf(float f) {
  unsigned u = __float_as_uint(f);
  u += 0x7FFFu + ((u >> 16) & 1u);   // round-to-nearest-even
  return (u16)(u >> 16);
}

static __device__ __forceinline__ void gload16(const void* g, void* l) {
  __builtin_amdgcn_global_load_lds((const __attribute__((address_space(1))) void*)g,
                                   (__attribute__((address_space(3))) void*)l, 16, 0, 0);
}

// ---------------- f32 -> bf16 conversion (8 f32 in, 8 bf16 out per thread) ----
__global__ void cvt_f32_to_bf16(const float* __restrict__ in, u16* __restrict__ out, int n8) {
  const int stride = gridDim.x * blockDim.x;
  for (int i = blockIdx.x * blockDim.x + threadIdx.x; i < n8; i += stride) {
    const float4v* p = (const float4v*)in + (size_t)i * 2;
    float4v a = p[0], b = p[1];
    union { u16 h[8]; int4v v; } r;
    r.h[0] = f2bf(a.x); r.h[1] = f2bf(a.y); r.h[2] = f2bf(a.z); r.h[3] = f2bf(a.w);
    r.h[4] = f2bf(b.x); r.h[5] = f2bf(b.y); r.h[6] = f2bf(b.z); r.h[7] = f2bf(b.w);
    ((int4v*)out)[i] = r.v;
  }
}

// ---------------- GEMM1: qout[M,Nc] = qbf[M,K] * w1bf[Nc,K]^T + b1, bf16 out --
__global__ __launch_bounds__(256, 2)
void gemm1_kernel(const u16* __restrict__ A, const u16* __restrict__ Bm,
                  const float* __restrict__ bias, u16* __restrict__ C,
                  int Nc, int K)
{
  const int lane = threadIdx.x & 63;
  const int wave = threadIdx.x >> 6;
  const int wr = wave >> 1, wc = wave & 1;
  const int tM = blockIdx.y << 7;
  const int tN = blockIdx.x << 7;

  __shared__ u16 As[128 * 32];
  __shared__ u16 Bs[128 * 32];

  const int srow = wave * 16 + (lane >> 2);
  const int scol = (lane & 3) * 8;
  const u16* ga0 = A  + (size_t)(tM + srow)      * K + scol;
  const u16* ga1 = A  + (size_t)(tM + srow + 64) * K + scol;
  const u16* gb0 = Bm + (size_t)(tN + srow)      * K + scol;
  const u16* gb1 = Bm + (size_t)(tN + srow + 64) * K + scol;
  u16* lA0 = As + wave * 512;
  u16* lA1 = As + 2048 + wave * 512;
  u16* lB0 = Bs + wave * 512;
  u16* lB1 = Bs + 2048 + wave * 512;

  f32x4 acc[4][4];
  #pragma unroll
  for (int m = 0; m < 4; ++m)
    #pragma unroll
    for (int n = 0; n < 4; ++n)
      acc[m][n] = (f32x4){0.f, 0.f, 0.f, 0.f};

  const int arow = wr * 64 + (lane & 15);
  const int brow = wc * 64 + (lane & 15);
  const int kblk = (lane >> 4) * 8;

  for (int k0 = 0; k0 < K; k0 += 32) {
    __syncthreads();
    gload16(ga0 + k0, lA0);
    gload16(ga1 + k0, lA1);
    gload16(gb0 + k0, lB0);
    gload16(gb1 + k0, lB1);
    asm volatile("s_waitcnt vmcnt(0)" ::: "memory");
    __syncthreads();

    short8 af[4], bfr[4];
    #pragma unroll
    for (int m = 0; m < 4; ++m)
      af[m] = *(const short8*)(As + (arow + m * 16) * 32 + kblk);
    #pragma unroll
    for (int n = 0; n < 4; ++n)
      bfr[n] = *(const short8*)(Bs + (brow + n * 16) * 32 + kblk);

    #pragma unroll
    for (int m = 0; m < 4; ++m)
      #pragma unroll
      for (int n = 0; n < 4; ++n)
        acc[m][n] = __builtin_amdgcn_mfma_f32_16x16x32_bf16(af[m], bfr[n], acc[m][n], 0, 0, 0);
  }

  const int r0 = tM + wr * 64 + (lane >> 4) * 4;
  const int c0 = tN + wc * 64 + (lane & 15);
  #pragma unroll
  for (int m = 0; m < 4; ++m)
    #pragma unroll
    for (int n = 0; n < 4; ++n) {
      const int col = c0 + n * 16;
      const float bv = bias[col];
      #pragma unroll
      for (int j = 0; j < 4; ++j)
        C[(size_t)(r0 + m * 16 + j) * Nc + col] = f2bf(acc[m][n][j] + bv);
    }
}

// ---------------- GEMM2 (batched, fused epilogue): ----------------------------
// attn[b] = qout[b] @ qout[b]^T (f32); out[b] = dinv_i * attn * dinv_j
__global__ __launch_bounds__(256, 2)
void gemm2_fused(const u16* __restrict__ Qbase, const float* __restrict__ dinv,
                 float* __restrict__ attnBase, float* __restrict__ outBase)
{
  const int z = blockIdx.z;
  const u16* A = Qbase + (size_t)z * N_ * D_;
  const int lane = threadIdx.x & 63;
  const int wave = threadIdx.x >> 6;
  const int wr = wave >> 1, wc = wave & 1;
  const int tM = blockIdx.y << 7;
  const int tN = blockIdx.x << 7;

  __shared__ u16 As[128 * 32];
  __shared__ u16 Bs[128 * 32];

  const int srow = wave * 16 + (lane >> 2);
  const int scol = (lane & 3) * 8;
  const u16* ga0 = A + (size_t)(tM + srow)      * D_ + scol;
  const u16* ga1 = A + (size_t)(tM + srow + 64) * D_ + scol;
  const u16* gb0 = A + (size_t)(tN + srow)      * D_ + scol;
  const u16* gb1 = A + (size_t)(tN + srow + 64) * D_ + scol;
  u16* lA0 = As + wave * 512;
  u16* lA1 = As + 2048 + wave * 512;
  u16* lB0 = Bs + wave * 512;
  u16* lB1 = Bs + 2048 + wave * 512;

  f32x4 acc[4][4];
  #pragma unroll
  for (int m = 0; m < 4; ++m)
    #pragma unroll
    for (int n = 0; n < 4; ++n)
      acc[m][n] = (f32x4){0.f, 0.f, 0.f, 0.f};

  const int arow = wr * 64 + (lane & 15);
  const int brow = wc * 64 + (lane & 15);
  const int kblk = (lane >> 4) * 8;

  for (int k0 = 0; k0 < D_; k0 += 32) {
    __syncthreads();
    gload16(ga0 + k0, lA0);
    gload16(ga1 + k0, lA1);
    gload16(gb0 + k0, lB0);
    gload16(gb1 + k0, lB1);
    asm volatile("s_waitcnt vmcnt(0)" ::: "memory");
    __syncthreads();

    short8 af[4], bfr[4];
    #pragma unroll
    for (int m = 0; m < 4; ++m)
      af[m] = *(const short8*)(As + (arow + m * 16) * 32 + kblk);
    #pragma unroll
    for (int n = 0; n < 4; ++n)
      bfr[n] = *(const short8*)(Bs + (brow + n * 16) * 32 + kblk);

    #pragma unroll
    for (int m = 0; m < 4; ++m)
      #pragma unroll
      for (int n = 0; n < 4; ++n)
        acc[m][n] = __builtin_amdgcn_mfma_f32_16x16x32_bf16(af[m], bfr[n], acc[m][n], 0, 0, 0);
  }

  float* Cattn = attnBase + (size_t)z * N_ * N_;
  float* Cout  = outBase  + (size_t)z * N_ * N_;
  const float* dv = dinv + z * N_;

  const int r0 = tM + wr * 64 + (lane >> 4) * 4;
  const int c0 = tN + wc * 64 + (lane & 15);
  float di[4][4];
  #pragma unroll
  for (int m = 0; m < 4; ++m)
    #pragma unroll
    for (int j = 0; j < 4; ++j)
      di[m][j] = dv[r0 + m * 16 + j];

  #pragma unroll
  for (int m = 0; m < 4; ++m)
    #pragma unroll
    for (int n = 0; n < 4; ++n) {
      const int col = c0 + n * 16;
      const float dj = dv[col];
      #pragma unroll
      for (int j = 0; j < 4; ++j) {
        const size_t off = (size_t)(r0 + m * 16 + j) * N_ + col;
        const float a = acc[m][n][j];
        Cattn[off] = a;
        Cout[off]  = a * di[m][j] * dj;
      }
    }
}

// ---------------- exact f32 rowsum path ---------------------------------------
// qsum[b,d] = sum_i q[b,i,d]
__global__ void qsum_kernel(const float* __restrict__ q, float* __restrict__ qsum) {
  const int b   = blockIdx.z;
  const int d   = blockIdx.x * 256 + threadIdx.x;
  const int r0  = blockIdx.y * 256;
  const float* p = q + ((size_t)b * N_ + r0) * D_ + d;
  float acc = 0.f;
  for (int r = 0; r < 256; ++r) acc += p[(size_t)r * D_];
  atomicAdd(&qsum[b * D_ + d], acc);
}

// s[b,e] = sum_d qsum[b,d] * W1[e,d] + N*b1[e]
__global__ void s_kernel(const float* __restrict__ qsum, const float* __restrict__ W1,
                         const float* __restrict__ b1, float* __restrict__ s) {
  const int idx = blockIdx.x * 256 + threadIdx.x;   // b*D + e
  const int b = idx >> 10, e = idx & (D_ - 1);
  const int d0 = blockIdx.y * 256;
  const float4v* wp = (const float4v*)(W1 + (size_t)e * D_ + d0);
  const float4v* qp = (const float4v*)(qsum + b * D_ + d0);
  float acc = 0.f;
  #pragma unroll 4
  for (int t = 0; t < 64; ++t) {
    float4v w = wp[t], qv = qp[t];
    acc += w.x * qv.x + w.y * qv.y + w.z * qv.z + w.w * qv.w;
  }
  if (blockIdx.y == 0) acc += (float)N_ * b1[e];
  atomicAdd(&s[b * D_ + e], acc);
}

// t[b,d] = sum_e W1[e,d] * s[b,e]
__global__ void t_kernel(const float* __restrict__ W1, const float* __restrict__ s,
                         float* __restrict__ tv) {
  const int idx = blockIdx.x * 256 + threadIdx.x;   // b*D + d
  const int b = idx >> 10, d = idx & (D_ - 1);
  const int e0 = blockIdx.y * 256;
  const float* wp = W1 + (size_t)e0 * D_ + d;
  const float* sp = s + b * D_ + e0;
  float acc = 0.f;
  #pragma unroll 8
  for (int e = 0; e < 256; ++e) acc += wp[(size_t)e * D_] * sp[e];
  atomicAdd(&tv[b * D_ + d], acc);
}

// c[b] = sum_e b1[e] * s[b,e]
__global__ void c_kernel(const float* __restrict__ b1, const float* __restrict__ s,
                         float* __restrict__ c) {
  const int b = blockIdx.x;
  const int tid = threadIdx.x;
  float acc = 0.f;
  #pragma unroll
  for (int t = 0; t < 4; ++t) {
    const int e = tid + t * 256;
    acc += b1[e] * s[b * D_ + e];
  }
  __shared__ float red[4];
  #pragma unroll
  for (int off = 32; off; off >>= 1) acc += __shfl_down(acc, off);
  if ((tid & 63) == 0) red[tid >> 6] = acc;
  __syncthreads();
  if (tid == 0) c[b] = red[0] + red[1] + red[2] + red[3];
}

// dinv[b,i] = rsqrt(max(q[b,i,:] . t[b,:] + c[b], 1))
__global__ void rowdinv_kernel(const float* __restrict__ q, const float* __restrict__ tv,
                               const float* __restrict__ c, float* __restrict__ dinv) {
  const int row  = blockIdx.x * 4 + (threadIdx.x >> 6);   // [0, B*N)
  const int lane = threadIdx.x & 63;
  const int b    = row >> 11;
  const float4v* p  = (const float4v*)(q + (size_t)row * D_);
  const float4v* tp = (const float4v*)(tv + b * D_);
  float acc = 0.f;
  #pragma unroll
  for (int it = 0; it < 4; ++it) {
    float4v qv = p[it * 64 + lane];
    float4v tw = tp[it * 64 + lane];
    acc += qv.x * tw.x + qv.y * tw.y + qv.z * tw.z + qv.w * tw.w;
  }
  #pragma unroll
  for (int off = 32; off; off >>= 1) acc += __shfl_down(acc, off);
  if (lane == 0) dinv[row] = rsqrtf(fmaxf(acc + c[b], 1.0f));
}

extern "C" void kernel_launch(void* const* d_in, const int* in_sizes, int n_in,
                              void* d_out, int out_size, void* d_ws, size_t ws_size,
                              hipStream_t stream) {
  const float* q  = (const float*)d_in[0];
  // d_in[1] = k (unused), d_in[2] = v (unused)
  const float* W1 = (const float*)d_in[3];
  const float* b1 = (const float*)d_in[4];

  float* out  = (float*)d_out;                      // [B,N,N] normalized
  float* attn = out + (size_t)B_ * N_ * N_;         // [B,N,N] raw attn

  char* ws = (char*)d_ws;
  u16*   qbf  = (u16*)ws;                                   // 32 MiB
  u16*   qout = (u16*)(ws + (size_t)33554432);              // 32 MiB
  u16*   w1bf = (u16*)(ws + (size_t)67108864);              // 2 MiB
  float* qsum = (float*)(ws + (size_t)69206016);            // 32 KiB
  float* s    = (float*)(ws + (size_t)69238784);            // 32 KiB
  float* tv   = (float*)(ws + (size_t)69271552);            // 32 KiB
  float* c    = (float*)(ws + (size_t)69304320);            // 256 B
  float* dinv = (float*)(ws + (size_t)69304576);            // 64 KiB

  // zero the accumulated stats (qsum, s, t, c) in one memset
  hipMemsetAsync(qsum, 0, 3 * B_ * D_ * sizeof(float) + 256, stream);

  // 1. convert q and W1 to bf16
  cvt_f32_to_bf16<<<2048, 256, 0, stream>>>(q, qbf, B_ * N_ * D_ / 8);
  cvt_f32_to_bf16<<<512, 256, 0, stream>>>(W1, w1bf, D_ * D_ / 8);

  // 2. GEMM1: qout[16384,1024] = qbf @ w1bf^T + b1   (bf16 out)
  dim3 g1(D_ / 128, (B_ * N_) / 128, 1);
  gemm1_kernel<<<g1, 256, 0, stream>>>(qbf, w1bf, b1, qout, D_, D_);

  // 3. exact f32 rowsum: rowsum[b,i] = q[b,i,:].t[b,:] + c[b]
  qsum_kernel<<<dim3(D_ / 256, N_ / 256, B_), 256, 0, stream>>>(q, qsum);
  s_kernel<<<dim3(B_ * D_ / 256, 4), 256, 0, stream>>>(qsum, W1, b1, s);
  t_kernel<<<dim3(B_ * D_ / 256, 4), 256, 0, stream>>>(W1, s, tv);
  c_kernel<<<B_, 256, 0, stream>>>(b1, s, c);
  rowdinv_kernel<<<(B_ * N_) / 4, 256, 0, stream>>>(q, tv, c, dinv);

  // 4. GEMM2 + fused normalization epilogue
  dim3 g2(N_ / 128, N_ / 128, B_);
  gemm2_fused<<<g2, 256, 0, stream>>>(qout, dinv, attn, out);
}

// Round 3
// 216.249 us; speedup vs baseline: 1.1289x; 1.1289x over previous
//
#include <hip/hip_runtime.h>

#define B_ 8
#define N_ 2048
#define D_ 1024

using u16 = unsigned short;
typedef __attribute__((ext_vector_type(8))) short short8;
typedef __attribute__((ext_vector_type(4))) float f32x4;
typedef __attribute__((ext_vector_type(4))) float float4v;
typedef __attribute__((ext_vector_type(4))) int int4v;

static __device__ __forceinline__ float bf2f(u16 h) {
  return __uint_as_float(((unsigned)h) << 16);
}
static __device__ __forceinline__ u16 f2bf(float f) {
  unsigned u = __float_as_uint(f);
  u += 0x7FFFu + ((u >> 16) & 1u);   // round-to-nearest-even
  return (u16)(u >> 16);
}

static __device__ __forceinline__ void gload16(const void* g, void* l) {
  __builtin_amdgcn_global_load_lds((const __attribute__((address_space(1))) void*)g,
                                   (__attribute__((address_space(3))) void*)l, 16, 0, 0);
}

// =====================================================================
// 8-phase 256x256 bf16 GEMM (C = A * B^T), K = 1024.
// 512 threads = 8 waves (2M x 4N); per-wave output 128x64.
// LDS: 2 buffers x (A[256][64] + B[256][64]) bf16 = 128 KiB.
// Swizzle: logical (row, colbyte) stored at row*128 + (colbyte ^ ((row&7)<<4)).
// Write side: linear global_load_lds dest + pre-swizzled global source.
// =====================================================================

__device__ __forceinline__ void stage(u16* __restrict__ L,
                                      const u16* __restrict__ gA,
                                      const u16* __restrict__ gB,
                                      int kof, int w) {
  #pragma unroll
  for (int i = 0; i < 4; ++i)
    gload16(gA + (size_t)(i * 64) * 1024 + kof, L + i * 4096 + w * 512);
  #pragma unroll
  for (int i = 0; i < 4; ++i)
    gload16(gB + (size_t)(i * 64) * 1024 + kof, L + 16384 + i * 4096 + w * 512);
}

__device__ __forceinline__ void ktile(const u16* __restrict__ Lb,
                                      int wr, int wc, int lane15, int ck0,
                                      f32x4 (&acc)[8][4]) {
  const u16* Ar = Lb + (wr * 128 + lane15) * 64;
  const u16* Br = Lb + 16384 + (wc * 64 + lane15) * 64;
  const int ck1 = ck0 ^ 32;
  short8 a[4], a2[4], b[4];

  // ---- phase 0: A m0-3 k0 + B n0-3 k0 (8 ds_read_b128) ----
  #pragma unroll
  for (int m = 0; m < 4; ++m) a[m] = *(const short8*)(Ar + m * 1024 + ck0);
  #pragma unroll
  for (int n = 0; n < 4; ++n) b[n] = *(const short8*)(Br + n * 1024 + ck0);
  __builtin_amdgcn_s_barrier();
  __builtin_amdgcn_s_setprio(1);
  #pragma unroll
  for (int m = 0; m < 4; ++m)
    #pragma unroll
    for (int n = 0; n < 4; ++n)
      acc[m][n] = __builtin_amdgcn_mfma_f32_16x16x32_bf16(a[m], b[n], acc[m][n], 0, 0, 0);
  __builtin_amdgcn_s_setprio(0);
  __builtin_amdgcn_s_barrier();

  // ---- phase 1: A m4-7 k0 (4 ds_read_b128) ----
  #pragma unroll
  for (int m = 0; m < 4; ++m) a2[m] = *(const short8*)(Ar + (m + 4) * 1024 + ck0);
  __builtin_amdgcn_s_barrier();
  __builtin_amdgcn_s_setprio(1);
  #pragma unroll
  for (int m = 0; m < 4; ++m)
    #pragma unroll
    for (int n = 0; n < 4; ++n)
      acc[m + 4][n] = __builtin_amdgcn_mfma_f32_16x16x32_bf16(a2[m], b[n], acc[m + 4][n], 0, 0, 0);
  __builtin_amdgcn_s_setprio(0);
  __builtin_amdgcn_s_barrier();

  // ---- phase 2: A m0-3 k1 + B n0-3 k1 ----
  #pragma unroll
  for (int m = 0; m < 4; ++m) a[m] = *(const short8*)(Ar + m * 1024 + ck1);
  #pragma unroll
  for (int n = 0; n < 4; ++n) b[n] = *(const short8*)(Br + n * 1024 + ck1);
  __builtin_amdgcn_s_barrier();
  __builtin_amdgcn_s_setprio(1);
  #pragma unroll
  for (int m = 0; m < 4; ++m)
    #pragma unroll
    for (int n = 0; n < 4; ++n)
      acc[m][n] = __builtin_amdgcn_mfma_f32_16x16x32_bf16(a[m], b[n], acc[m][n], 0, 0, 0);
  __builtin_amdgcn_s_setprio(0);
  __builtin_amdgcn_s_barrier();

  // ---- phase 3: A m4-7 k1 ----
  #pragma unroll
  for (int m = 0; m < 4; ++m) a2[m] = *(const short8*)(Ar + (m + 4) * 1024 + ck1);
  __builtin_amdgcn_s_barrier();
  __builtin_amdgcn_s_setprio(1);
  #pragma unroll
  for (int m = 0; m < 4; ++m)
    #pragma unroll
    for (int n = 0; n < 4; ++n)
      acc[m + 4][n] = __builtin_amdgcn_mfma_f32_16x16x32_bf16(a2[m], b[n], acc[m + 4][n], 0, 0, 0);
  __builtin_amdgcn_s_setprio(0);
  __builtin_amdgcn_s_barrier();
}

// MODE 0: C0 = bf16 out [M x 1024] with +bias     (GEMM1)
// MODE 1: batched symmetric, dual f32 out: attn=C0raw, out=C1 scaled by dinv (GEMM2)
template<int MODE>
__global__ __launch_bounds__(512, 2)
void gemm8p(const u16* __restrict__ Abase, const u16* __restrict__ Bbase,
            const float* __restrict__ aux,   // bias (MODE0) or dinv (MODE1)
            void* __restrict__ C0, float* __restrict__ C1)
{
  __shared__ u16 lds[2][32768];
  const int tid = threadIdx.x;
  const int w = tid >> 6, l = tid & 63;

  int tm0, tn0, z = 0;
  if (MODE == 0) {
    const int bid = blockIdx.x;                 // 256 blocks
    const int s = (bid & 7) * 32 + (bid >> 3);  // XCD-contiguous
    tm0 = (s >> 2) << 8;
    tn0 = (s & 3) << 8;
  } else {
    const int bid = blockIdx.x;                 // 512 blocks
    const int s = (bid & 7) * 64 + (bid >> 3);  // each XCD owns one batch
    z  = s >> 6;
    tm0 = ((s >> 3) & 7) << 8;
    tn0 = (s & 7) << 8;
  }
  const u16* A  = Abase + (MODE ? (size_t)z * N_ * D_ : 0);
  const u16* Bm = (MODE ? A : Bbase);

  // ---- staging source (pre-swizzled global col so linear LDS dest = swizzled layout)
  const int sr = w * 8 + (l >> 3);                       // row within 64-row round
  const int sc = (((l & 7) ^ (l >> 3)) << 4) >> 1;       // element col (swizzled)
  const u16* gA = A  + (size_t)(tm0 + sr) * 1024 + sc;
  const u16* gB = Bm + (size_t)(tn0 + sr) * 1024 + sc;

  // ---- fragment read addressing
  const int lane15 = l & 15, lhi = l >> 4;
  const int ck0 = ((lhi << 4) ^ ((l & 7) << 4)) >> 1;    // element col, kh=0
  const int wr = w >> 2, wc = w & 3;

  f32x4 acc[8][4];
  #pragma unroll
  for (int m = 0; m < 8; ++m)
    #pragma unroll
    for (int n = 0; n < 4; ++n)
      acc[m][n] = (f32x4){0.f, 0.f, 0.f, 0.f};

  // prologue: issue K-tiles 0,1
  stage(&lds[0][0], gA, gB, 0, w);
  stage(&lds[1][0], gA, gB, 64, w);

  for (int t = 0; t < 16; t += 2) {
    asm volatile("s_waitcnt vmcnt(8)" ::: "memory");   // tile t landed (all waves after barrier)
    __builtin_amdgcn_s_barrier();
    ktile(&lds[0][0], wr, wc, lane15, ck0, acc);
    stage(&lds[0][0], gA, gB, ((t + 2) & 15) * 64, w); // buf0 free (post-barrier)
    asm volatile("s_waitcnt vmcnt(8)" ::: "memory");   // tile t+1 landed
    __builtin_amdgcn_s_barrier();
    ktile(&lds[1][0], wr, wc, lane15, ck0, acc);
    stage(&lds[1][0], gA, gB, ((t + 3) & 15) * 64, w);
  }
  asm volatile("s_waitcnt vmcnt(0)" ::: "memory");     // drain DMA before endpgm

  // ---- epilogue: C/D layout col=lane&15, row=(lane>>4)*4+j ----
  const int rbase = tm0 + wr * 128 + lhi * 4;
  const int cbase = tn0 + wc * 64 + lane15;

  if (MODE == 0) {
    u16* C = (u16*)C0;
    #pragma unroll
    for (int m = 0; m < 8; ++m)
      #pragma unroll
      for (int n = 0; n < 4; ++n) {
        const int col = cbase + n * 16;
        const float bv = aux[col];
        #pragma unroll
        for (int j = 0; j < 4; ++j)
          C[(size_t)(rbase + m * 16 + j) * 1024 + col] = f2bf(acc[m][n][j] + bv);
      }
  } else {
    float* Cattn = (float*)C0 + (size_t)z * N_ * N_;
    float* Cout  = C1 + (size_t)z * N_ * N_;
    const float* dv = aux + z * N_;
    float di[8][4];
    #pragma unroll
    for (int m = 0; m < 8; ++m)
      #pragma unroll
      for (int j = 0; j < 4; ++j)
        di[m][j] = dv[rbase + m * 16 + j];
    #pragma unroll
    for (int m = 0; m < 8; ++m)
      #pragma unroll
      for (int n = 0; n < 4; ++n) {
        const int col = cbase + n * 16;
        const float dj = dv[col];
        #pragma unroll
        for (int j = 0; j < 4; ++j) {
          const size_t off = (size_t)(rbase + m * 16 + j) * N_ + col;
          const float a = acc[m][n][j];
          Cattn[off] = a;
          Cout[off]  = a * di[m][j] * dj;
        }
      }
  }
}

// ---------------- fused q f32->bf16 cvt + column sums -------------------------
// 256 blocks x 256 threads; thread owns (b, 32-row chunk, 8-col group).
__global__ void cvt_q_qsum(const float* __restrict__ q, u16* __restrict__ qbf,
                           float* __restrict__ qsum) {
  const int wi = blockIdx.x * 256 + threadIdx.x;
  const int d0 = (wi & 127) * 8;
  const int rc = (wi >> 7) & 63;
  const int b  = wi >> 13;
  const size_t base = ((size_t)b * N_ + rc * 32) * D_ + d0;
  float s[8];
  #pragma unroll
  for (int k = 0; k < 8; ++k) s[k] = 0.f;
  for (int r = 0; r < 32; ++r) {
    const float4v* p = (const float4v*)(q + base + (size_t)r * D_);
    float4v x = p[0], y = p[1];
    union { u16 h[8]; int4v v; } o;
    o.h[0] = f2bf(x.x); o.h[1] = f2bf(x.y); o.h[2] = f2bf(x.z); o.h[3] = f2bf(x.w);
    o.h[4] = f2bf(y.x); o.h[5] = f2bf(y.y); o.h[6] = f2bf(y.z); o.h[7] = f2bf(y.w);
    *(int4v*)(qbf + base + (size_t)r * D_) = o.v;
    s[0] += x.x; s[1] += x.y; s[2] += x.z; s[3] += x.w;
    s[4] += y.x; s[5] += y.y; s[6] += y.z; s[7] += y.w;
  }
  float* qs = qsum + b * D_ + d0;
  #pragma unroll
  for (int k = 0; k < 8; ++k) atomicAdd(qs + k, s[k]);
}

// ---------------- W1 f32 -> bf16 ---------------------------------------------
__global__ void cvt_f32_to_bf16(const float* __restrict__ in, u16* __restrict__ out, int n8) {
  const int stride = gridDim.x * blockDim.x;
  for (int i = blockIdx.x * blockDim.x + threadIdx.x; i < n8; i += stride) {
    const float4v* p = (const float4v*)in + (size_t)i * 2;
    float4v a = p[0], b = p[1];
    union { u16 h[8]; int4v v; } r;
    r.h[0] = f2bf(a.x); r.h[1] = f2bf(a.y); r.h[2] = f2bf(a.z); r.h[3] = f2bf(a.w);
    r.h[4] = f2bf(b.x); r.h[5] = f2bf(b.y); r.h[6] = f2bf(b.z); r.h[7] = f2bf(b.w);
    ((int4v*)out)[i] = r.v;
  }
}

// ---------------- exact f32 rowsum stats --------------------------------------
// s[b,e] = sum_d qsum[b,d] * W1[e,d] + N*b1[e]
__global__ void s_kernel(const float* __restrict__ qsum, const float* __restrict__ W1,
                         const float* __restrict__ b1, float* __restrict__ s) {
  const int idx = blockIdx.x * 256 + threadIdx.x;   // b*D + e
  const int b = idx >> 10, e = idx & (D_ - 1);
  const int d0 = blockIdx.y * 256;
  const float4v* wp = (const float4v*)(W1 + (size_t)e * D_ + d0);
  const float4v* qp = (const float4v*)(qsum + b * D_ + d0);
  float acc = 0.f;
  #pragma unroll 4
  for (int t = 0; t < 64; ++t) {
    float4v wv = wp[t], qv = qp[t];
    acc += wv.x * qv.x + wv.y * qv.y + wv.z * qv.z + wv.w * qv.w;
  }
  if (blockIdx.y == 0) acc += (float)N_ * b1[e];
  atomicAdd(&s[b * D_ + e], acc);
}

// t[b,d] = sum_e W1[e,d] * s[b,e]
__global__ void t_kernel(const float* __restrict__ W1, const float* __restrict__ s,
                         float* __restrict__ tv) {
  const int idx = blockIdx.x * 256 + threadIdx.x;   // b*D + d
  const int b = idx >> 10, d = idx & (D_ - 1);
  const int e0 = blockIdx.y * 256;
  const float* wp = W1 + (size_t)e0 * D_ + d;
  const float* sp = s + b * D_ + e0;
  float acc = 0.f;
  #pragma unroll 8
  for (int e = 0; e < 256; ++e) acc += wp[(size_t)e * D_] * sp[e];
  atomicAdd(&tv[b * D_ + d], acc);
}

// c[b] = sum_e b1[e] * s[b,e]
__global__ void c_kernel(const float* __restrict__ b1, const float* __restrict__ s,
                         float* __restrict__ c) {
  const int b = blockIdx.x;
  const int tid = threadIdx.x;
  float acc = 0.f;
  #pragma unroll
  for (int t = 0; t < 4; ++t) {
    const int e = tid + t * 256;
    acc += b1[e] * s[b * D_ + e];
  }
  __shared__ float red[4];
  #pragma unroll
  for (int off = 32; off; off >>= 1) acc += __shfl_down(acc, off);
  if ((tid & 63) == 0) red[tid >> 6] = acc;
  __syncthreads();
  if (tid == 0) c[b] = red[0] + red[1] + red[2] + red[3];
}

// dinv[b,i] = rsqrt(max(q[b,i,:] . t[b,:] + c[b], 1))
__global__ void rowdinv_kernel(const float* __restrict__ q, const float* __restrict__ tv,
                               const float* __restrict__ c, float* __restrict__ dinv) {
  const int row  = blockIdx.x * 4 + (threadIdx.x >> 6);   // [0, B*N)
  const int lane = threadIdx.x & 63;
  const int b    = row >> 11;
  const float4v* p  = (const float4v*)(q + (size_t)row * D_);
  const float4v* tp = (const float4v*)(tv + b * D_);
  float acc = 0.f;
  #pragma unroll
  for (int it = 0; it < 4; ++it) {
    float4v qv = p[it * 64 + lane];
    float4v tw = tp[it * 64 + lane];
    acc += qv.x * tw.x + qv.y * tw.y + qv.z * tw.z + qv.w * tw.w;
  }
  #pragma unroll
  for (int off = 32; off; off >>= 1) acc += __shfl_down(acc, off);
  if (lane == 0) dinv[row] = rsqrtf(fmaxf(acc + c[b], 1.0f));
}

extern "C" void kernel_launch(void* const* d_in, const int* in_sizes, int n_in,
                              void* d_out, int out_size, void* d_ws, size_t ws_size,
                              hipStream_t stream) {
  const float* q  = (const float*)d_in[0];
  // d_in[1] = k (unused), d_in[2] = v (unused)
  const float* W1 = (const float*)d_in[3];
  const float* b1 = (const float*)d_in[4];

  float* out  = (float*)d_out;                      // [B,N,N] normalized
  float* attn = out + (size_t)B_ * N_ * N_;         // [B,N,N] raw attn

  char* ws = (char*)d_ws;
  u16*   qbf  = (u16*)ws;                                   // 32 MiB
  u16*   qout = (u16*)(ws + (size_t)33554432);              // 32 MiB
  u16*   w1bf = (u16*)(ws + (size_t)67108864);              // 2 MiB
  float* qsum = (float*)(ws + (size_t)69206016);            // 32 KiB
  float* s    = (float*)(ws + (size_t)69238784);            // 32 KiB
  float* tv   = (float*)(ws + (size_t)69271552);            // 32 KiB
  float* c    = (float*)(ws + (size_t)69304320);            // 256 B
  float* dinv = (float*)(ws + (size_t)69304576);            // 64 KiB

  // zero the accumulated stats (qsum, s, t, c)
  hipMemsetAsync(qsum, 0, 3 * B_ * D_ * sizeof(float) + 256, stream);

  // 1. convert q (+column sums) and W1 to bf16
  cvt_q_qsum<<<256, 256, 0, stream>>>(q, qbf, qsum);
  cvt_f32_to_bf16<<<512, 256, 0, stream>>>(W1, w1bf, D_ * D_ / 8);

  // 2. GEMM1 (8-phase 256^2): qout = qbf @ w1bf^T + b1  (bf16 out)
  gemm8p<0><<<256, 512, 0, stream>>>(qbf, w1bf, b1, qout, nullptr);

  // 3. exact f32 rowsum: rowsum[b,i] = q[b,i,:].t[b,:] + c[b]
  s_kernel<<<dim3(B_ * D_ / 256, 4), 256, 0, stream>>>(qsum, W1, b1, s);
  t_kernel<<<dim3(B_ * D_ / 256, 4), 256, 0, stream>>>(W1, s, tv);
  c_kernel<<<B_, 256, 0, stream>>>(b1, s, c);
  rowdinv_kernel<<<(B_ * N_) / 4, 256, 0, stream>>>(q, tv, c, dinv);

  // 4. GEMM2 (8-phase 256^2, batched) + fused normalization epilogue
  gemm8p<1><<<512, 512, 0, stream>>>(qout, nullptr, dinv, attn, out);
}